// Round 7
// baseline (1056.385 us; speedup 1.0000x reference)
//
#include <hip/hip_runtime.h>
#include <hip/hip_bf16.h>
#include <math.h>

#define TM 64   // nodes per ffn block
#define XP 20   // padded xs row stride (16B-aligned rows)

typedef float v2f __attribute__((ext_vector_type(2)));

__device__ __forceinline__ v2f fma2(v2f a, v2f b, v2f c) {
    return __builtin_elementwise_fma(a, b, c);
}
__device__ __forceinline__ v2f splat2(float s) { return (v2f){s, s}; }
__device__ __forceinline__ v2f max02(v2f a) {
    return (v2f){fmaxf(a.x, 0.0f), fmaxf(a.y, 0.0f)};
}
// opaque 0 pinned in a VGPR: forces following address math to VMEM (global_load),
// so weight streams ride vmcnt instead of sharing lgkmcnt with ds_read.
__device__ __forceinline__ int opaque_zero() {
    int z = 0;
    asm volatile("" : "+v"(z));
    return z;
}

// ---------------- fused FFN + decoder: coords -> emb, writes xs = dinv * [features, emb, 0pad] ----------------
__global__ __launch_bounds__(256, 4) void ffn_kernel(
    const float* __restrict__ coords, const float* __restrict__ features,
    const float* __restrict__ dinv,
    const float* __restrict__ fw0, const float* __restrict__ fb0,
    const float* __restrict__ fg0, const float* __restrict__ fe0,
    const float* __restrict__ fw1, const float* __restrict__ fb1,
    const float* __restrict__ fg1, const float* __restrict__ fe1,
    const float* __restrict__ fw2, const float* __restrict__ fb2,
    const float* __restrict__ fg2, const float* __restrict__ fe2,
    const float* __restrict__ fw3, const float* __restrict__ fb3,
    const float* __restrict__ dw0, const float* __restrict__ db0,
    const float* __restrict__ dw1, const float* __restrict__ db1,
    const float* __restrict__ dw2, const float* __restrict__ db2,
    float* __restrict__ xout, int n_nodes)
{
    __shared__ float hbuf[128][TM];   // [feature][node], 32 KB
    __shared__ float ps1[4][64];      // LN partial sums
    __shared__ float ps2[4][64];      // LN partial sumsq

    const int t    = threadIdx.x;
    const int lane = t & 63;
    const int w    = __builtin_amdgcn_readfirstlane(t >> 6);
    const int jw   = w * 32;
    const int n0   = blockIdx.x * TM;
    const int opq  = opaque_zero();   // per-thread VGPR 0

    int g = n0 + lane;
    if (g >= n_nodes) g = n_nodes - 1;

    v2f acc[16];   // outs (jw+2q, jw+2q+1)

    auto lnorm = [&](const float* __restrict__ gam, const float* __restrict__ bet) {
        float s1 = 0.f, s2 = 0.f;
        #pragma unroll
        for (int q = 0; q < 16; q++) {
            s1 += acc[q].x + acc[q].y;
            s2 += acc[q].x * acc[q].x + acc[q].y * acc[q].y;
        }
        ps1[w][lane] = s1; ps2[w][lane] = s2;
        __syncthreads();
        float t1 = ps1[0][lane] + ps1[1][lane] + ps1[2][lane] + ps1[3][lane];
        float t2 = ps2[0][lane] + ps2[1][lane] + ps2[2][lane] + ps2[3][lane];
        float mean = t1 * (1.0f / 128.0f);
        float var  = t2 * (1.0f / 128.0f) - mean * mean;
        float inv  = rsqrtf(var + 1e-5f);
        v2f mean2 = splat2(mean), inv2 = splat2(inv);
        #pragma unroll
        for (int q = 0; q < 16; q++) {
            v2f gm = *(const v2f*)&gam[jw + 2 * q];   // uniform s_load (small)
            v2f bt = *(const v2f*)&bet[jw + 2 * q];
            acc[q] = fma2((acc[q] - mean2) * inv2, gm, bt);
        }
    };

    auto store32 = [&]() {
        #pragma unroll
        for (int q = 0; q < 16; q++) {
            hbuf[jw + 2 * q][lane]     = acc[q].x;
            hbuf[jw + 2 * q + 1][lane] = acc[q].y;
        }
    };

    auto layer128 = [&](const float* __restrict__ W, const float* __restrict__ b) {
        #pragma unroll
        for (int q = 0; q < 16; q++) acc[q] = *(const v2f*)&b[jw + 2 * q];
        #pragma unroll 2
        for (int k = 0; k < 128; k++) {
            v2f av = splat2(hbuf[k][lane]);
            const float4* W4 = (const float4*)(W + (k * 128 + jw + opq));  // VMEM broadcast
            #pragma unroll
            for (int q4 = 0; q4 < 8; q4++) {
                float4 wv = W4[q4];
                v2f w01 = (v2f){wv.x, wv.y};
                v2f w23 = (v2f){wv.z, wv.w};
                acc[2 * q4]     = fma2(av, w01, acc[2 * q4]);
                acc[2 * q4 + 1] = fma2(av, w23, acc[2 * q4 + 1]);
            }
        }
    };

    // ---- layer 0: 2 -> 128, relu, LN ----
    {
        float2 c = *(const float2*)&coords[(size_t)g * 2];
        v2f cx = splat2(c.x), cy = splat2(c.y);
        #pragma unroll
        for (int q = 0; q < 16; q++) {
            int j = jw + 2 * q;
            v2f w0 = *(const v2f*)&fw0[j];
            v2f w1 = *(const v2f*)&fw0[128 + j];
            v2f bb = *(const v2f*)&fb0[j];
            acc[q] = max02(fma2(cx, w0, fma2(cy, w1, bb)));
        }
        lnorm(fg0, fe0);
        store32();
        __syncthreads();
    }

    // ---- layers 1..2: 128 -> 128, relu, LN ----
    layer128(fw1, fb1);
    #pragma unroll
    for (int q = 0; q < 16; q++) acc[q] = max02(acc[q]);
    lnorm(fg1, fe1);
    store32();
    __syncthreads();

    layer128(fw2, fb2);
    #pragma unroll
    for (int q = 0; q < 16; q++) acc[q] = max02(acc[q]);
    lnorm(fg2, fe2);
    store32();
    __syncthreads();

    // ---- layer 3: 128 -> 128, relu only ----
    layer128(fw3, fb3);
    #pragma unroll
    for (int q = 0; q < 16; q++) acc[q] = max02(acc[q]);
    __syncthreads();
    store32();
    __syncthreads();

    // ---- decoder D0: 128 -> 64, tanh ----
    {
        const int j16 = w * 16;
        v2f d0[8];
        #pragma unroll
        for (int q = 0; q < 8; q++) d0[q] = *(const v2f*)&db0[j16 + 2 * q];
        #pragma unroll 2
        for (int k = 0; k < 128; k++) {
            v2f av = splat2(hbuf[k][lane]);
            const float4* W4 = (const float4*)(dw0 + (k * 64 + j16 + opq));
            #pragma unroll
            for (int q4 = 0; q4 < 4; q4++) {
                float4 wv = W4[q4];
                d0[2 * q4]     = fma2(av, (v2f){wv.x, wv.y}, d0[2 * q4]);
                d0[2 * q4 + 1] = fma2(av, (v2f){wv.z, wv.w}, d0[2 * q4 + 1]);
            }
        }
        #pragma unroll
        for (int q = 0; q < 8; q++) d0[q] = (v2f){tanhf(d0[q].x), tanhf(d0[q].y)};
        __syncthreads();
        #pragma unroll
        for (int q = 0; q < 8; q++) {
            hbuf[j16 + 2 * q][lane]     = d0[q].x;
            hbuf[j16 + 2 * q + 1][lane] = d0[q].y;
        }
        __syncthreads();
    }

    // ---- decoder D1: 64 -> 32, tanh ----
    {
        const int j8 = w * 8;
        v2f d1[4];
        #pragma unroll
        for (int q = 0; q < 4; q++) d1[q] = *(const v2f*)&db1[j8 + 2 * q];
        #pragma unroll 4
        for (int k = 0; k < 64; k++) {
            v2f av = splat2(hbuf[k][lane]);
            const float4* W4 = (const float4*)(dw1 + (k * 32 + j8 + opq));
            #pragma unroll
            for (int q4 = 0; q4 < 2; q4++) {
                float4 wv = W4[q4];
                d1[2 * q4]     = fma2(av, (v2f){wv.x, wv.y}, d1[2 * q4]);
                d1[2 * q4 + 1] = fma2(av, (v2f){wv.z, wv.w}, d1[2 * q4 + 1]);
            }
        }
        #pragma unroll
        for (int q = 0; q < 4; q++) d1[q] = (v2f){tanhf(d1[q].x), tanhf(d1[q].y)};
        __syncthreads();
        #pragma unroll
        for (int q = 0; q < 4; q++) {
            hbuf[j8 + 2 * q][lane]     = d1[q].x;
            hbuf[j8 + 2 * q + 1][lane] = d1[q].y;
        }
        __syncthreads();
    }

    // ---- decoder D2: 32 -> 16, linear ----
    {
        const int j4 = w * 4;
        v2f d2[2];
        #pragma unroll
        for (int q = 0; q < 2; q++) d2[q] = *(const v2f*)&db2[j4 + 2 * q];
        #pragma unroll 4
        for (int k = 0; k < 32; k++) {
            v2f av = splat2(hbuf[k][lane]);
            const float4* W4 = (const float4*)(dw2 + (k * 16 + j4 + opq));
            float4 wv = W4[0];
            d2[0] = fma2(av, (v2f){wv.x, wv.y}, d2[0]);
            d2[1] = fma2(av, (v2f){wv.z, wv.w}, d2[1]);
        }
        __syncthreads();
        hbuf[j4 + 0][lane] = d2[0].x;
        hbuf[j4 + 1][lane] = d2[0].y;
        hbuf[j4 + 2][lane] = d2[1].x;
        hbuf[j4 + 3][lane] = d2[1].y;
        __syncthreads();
    }

    // ---- write xs = dinv * [features(3), emb(16), pad0], stride XP=20 ----
    // lane = node, iterate j: hbuf reads conflict-free (consecutive lanes -> consecutive banks)
    {
        const int nn = t & 63;
        const int jg = t >> 6;             // 0..3, each handles 5 js
        int gg = n0 + nn;
        if (gg < n_nodes) {
            float dgg = dinv[gg];
            #pragma unroll
            for (int it = 0; it < 5; it++) {
                int j = jg * 5 + it;
                float v = (j < 3) ? features[(size_t)gg * 3 + j]
                                  : (j < 19 ? hbuf[j - 3][nn] : 0.0f);
                xout[(size_t)gg * XP + j] = v * dgg;
            }
        }
    }
}

// ---------------- CSR build ----------------
__global__ void deg_kernel(const int* __restrict__ row, int* __restrict__ cnt, int E_) {
    int e4 = (blockIdx.x * blockDim.x + threadIdx.x) * 4;
    if (e4 + 3 < E_) {
        int4 r = *(const int4*)&row[e4];
        atomicAdd(&cnt[r.x], 1); atomicAdd(&cnt[r.y], 1);
        atomicAdd(&cnt[r.z], 1); atomicAdd(&cnt[r.w], 1);
    } else {
        for (int e = e4; e < E_; e++) atomicAdd(&cnt[row[e]], 1);
    }
}

__global__ void scan1_kernel(const int* __restrict__ cnt, int* __restrict__ offs,
                             int* __restrict__ bsum, int n) {
    __shared__ int tmp[256];
    int t = threadIdx.x, b = blockIdx.x, i = b * 256 + t;
    int v = (i < n) ? cnt[i] : 0;
    tmp[t] = v; __syncthreads();
    #pragma unroll
    for (int d = 1; d < 256; d <<= 1) {
        int add = (t >= d) ? tmp[t - d] : 0;
        __syncthreads();
        tmp[t] += add;
        __syncthreads();
    }
    if (i < n) offs[i] = tmp[t] - v;
    if (t == 255) bsum[b] = tmp[t];
}

__global__ void scan2_kernel(int* __restrict__ bsum, int B) {
    __shared__ int tmp[512];
    int t = threadIdx.x;
    tmp[t] = (t < B) ? bsum[t] : 0; __syncthreads();
    #pragma unroll
    for (int d = 1; d < 512; d <<= 1) {
        int add = (t >= d) ? tmp[t - d] : 0;
        __syncthreads();
        tmp[t] += add;
        __syncthreads();
    }
    if (t < B) bsum[t] = tmp[t];
}

__global__ void scan3_kernel(int* __restrict__ offs, const int* __restrict__ bsum,
                             const int* __restrict__ cnt, int* __restrict__ fill,
                             float* __restrict__ dinv, int n) {
    int i = blockIdx.x * blockDim.x + threadIdx.x;
    if (i >= n) return;
    int b = i >> 8;
    int base = (b > 0) ? bsum[b - 1] : 0;
    int o = offs[i] + base;
    offs[i] = o;
    fill[i] = o;
    dinv[i] = rsqrtf((float)cnt[i] + 1.0f);
}

__global__ void scatter_kernel(const int* __restrict__ row, const int* __restrict__ col,
                               int* __restrict__ fill, int* __restrict__ es, int E_) {
    int e4 = (blockIdx.x * blockDim.x + threadIdx.x) * 4;
    if (e4 + 3 < E_) {
        int4 r = *(const int4*)&row[e4];
        int4 c = *(const int4*)&col[e4];
        es[atomicAdd(&fill[r.x], 1)] = c.x;
        es[atomicAdd(&fill[r.y], 1)] = c.y;
        es[atomicAdd(&fill[r.z], 1)] = c.z;
        es[atomicAdd(&fill[r.w], 1)] = c.w;
    } else {
        for (int e = e4; e < E_; e++) {
            int p = atomicAdd(&fill[row[e]], 1);
            es[p] = col[e];
        }
    }
}

// w_eff = cw2 @ ow (64), b_eff = cb2 @ ow + ob
__global__ void prep_kernel(const float* __restrict__ cw2, const float* __restrict__ cb2,
                            const float* __restrict__ ow, const float* __restrict__ ob,
                            float* __restrict__ wb) {
    int i = threadIdx.x;
    if (i < 64) {
        float a = 0.f;
        for (int j = 0; j < 64; j++) a += cw2[i * 64 + j] * ow[j];
        wb[i] = a;
    }
    if (i == 0) {
        float bb = 0.f;
        for (int j = 0; j < 64; j++) bb += cb2[j] * ow[j];
        wb[64] = bb + ob[0];
    }
}

// quad (4 lanes) per node: gather Σ xs[c] (float4 adds), combine, ×di, matmul 19x64 split
// 16 outs/lane, relu, dot w_eff, reduce -> ss[i] = dinv[i]*s[i]
__global__ __launch_bounds__(256) void node1g_kernel(
    const int* __restrict__ offs, const int* __restrict__ cnt, const int* __restrict__ es,
    const float* __restrict__ dinv, const float* __restrict__ xs,
    const float* __restrict__ cw1, const float* __restrict__ cb1,
    const float* __restrict__ wb, float* __restrict__ ss, int n)
{
    __shared__ float w[XP * 64];
    __shared__ float bbs[64];
    __shared__ float wes[64];
    for (int i = threadIdx.x; i < 19 * 64; i += 256) w[i] = cw1[i];
    for (int i = threadIdx.x; i < 64; i += 256) {
        w[19 * 64 + i] = 0.0f;        // pad row
        bbs[i] = cb1[i];
        wes[i] = wb[i];
    }
    __syncthreads();
    const int t  = threadIdx.x;
    const int ql = t & 3;
    const int i  = blockIdx.x * 64 + (t >> 2);
    if (i >= n) return;
    const float di = dinv[i];

    float4 a4[5];
    if (ql == 0) {  // self term xs[i]
        const float4* xi = (const float4*)(xs + (size_t)i * XP);
        #pragma unroll
        for (int q = 0; q < 5; q++) a4[q] = xi[q];
    } else {
        #pragma unroll
        for (int q = 0; q < 5; q++) a4[q] = make_float4(0.f, 0.f, 0.f, 0.f);
    }
    const int st = offs[i], dg = cnt[i];
    for (int e = ql; e < dg; e += 4) {
        int c = es[st + e];
        const float4* xc = (const float4*)(xs + (size_t)c * XP);
        #pragma unroll
        for (int q = 0; q < 5; q++) {
            float4 v = xc[q];
            a4[q].x += v.x; a4[q].y += v.y; a4[q].z += v.z; a4[q].w += v.w;
        }
    }
    // quad reduce + scale by di
    float a19[XP];
    #pragma unroll
    for (int q = 0; q < 5; q++) {
        float vx = a4[q].x, vy = a4[q].y, vz = a4[q].z, vw = a4[q].w;
        vx += __shfl_xor(vx, 1); vy += __shfl_xor(vy, 1);
        vz += __shfl_xor(vz, 1); vw += __shfl_xor(vw, 1);
        vx += __shfl_xor(vx, 2); vy += __shfl_xor(vy, 2);
        vz += __shfl_xor(vz, 2); vw += __shfl_xor(vw, 2);
        a19[4 * q]     = vx * di;
        a19[4 * q + 1] = vy * di;
        a19[4 * q + 2] = vz * di;
        a19[4 * q + 3] = vw * di;
    }

    // matmul: this lane's 16 outputs j in [ql*16, ql*16+16)
    const int j0 = ql * 16;
    v2f am[8];
    const v2f* w2  = (const v2f*)w;
    const v2f* bb2 = (const v2f*)bbs;
    #pragma unroll
    for (int q = 0; q < 8; q++) am[q] = bb2[j0 / 2 + q];
    #pragma unroll
    for (int k = 0; k < 19; k++) {
        v2f v = splat2(a19[k]);
        #pragma unroll
        for (int q = 0; q < 8; q++) am[q] = fma2(v, w2[k * 32 + j0 / 2 + q], am[q]);
    }
    const v2f* we2 = (const v2f*)wes;
    v2f sv2 = {0.f, 0.f};
    #pragma unroll
    for (int q = 0; q < 8; q++) sv2 = fma2(max02(am[q]), we2[j0 / 2 + q], sv2);
    float sv = sv2.x + sv2.y;
    sv += __shfl_xor(sv, 1);
    sv += __shfl_xor(sv, 2);
    if (ql == 0) ss[i] = di * sv;
}

// quad per node: out[i] = b_eff + di * (ss[i] + Σ ss[c])
__global__ __launch_bounds__(256) void outg_kernel(
    const int* __restrict__ offs, const int* __restrict__ cnt, const int* __restrict__ es,
    const float* __restrict__ dinv, const float* __restrict__ ss,
    const float* __restrict__ wb, float* __restrict__ out, int n)
{
    const int t  = threadIdx.x;
    const int ql = t & 3;
    const int i  = blockIdx.x * 64 + (t >> 2);
    if (i >= n) return;
    const int st = offs[i], dg = cnt[i];
    float sum = (ql == 0) ? ss[i] : 0.f;
    for (int e = ql; e < dg; e += 4) {
        int c = es[st + e];
        sum += ss[c];
    }
    sum += __shfl_xor(sum, 1);
    sum += __shfl_xor(sum, 2);
    if (ql == 0) out[i] = wb[64] + dinv[i] * sum;
}

extern "C" void kernel_launch(void* const* d_in, const int* in_sizes, int n_in,
                              void* d_out, int out_size, void* d_ws, size_t ws_size,
                              hipStream_t stream) {
    const float* coords   = (const float*)d_in[0];
    const float* features = (const float*)d_in[1];
    const int*   eidx     = (const int*)d_in[2];
    const float* fw0 = (const float*)d_in[3];
    const float* fb0 = (const float*)d_in[4];
    const float* fg0 = (const float*)d_in[5];
    const float* fe0 = (const float*)d_in[6];
    const float* fw1 = (const float*)d_in[7];
    const float* fb1 = (const float*)d_in[8];
    const float* fg1 = (const float*)d_in[9];
    const float* fe1 = (const float*)d_in[10];
    const float* fw2 = (const float*)d_in[11];
    const float* fb2 = (const float*)d_in[12];
    const float* fg2 = (const float*)d_in[13];
    const float* fe2 = (const float*)d_in[14];
    const float* fw3 = (const float*)d_in[15];
    const float* fb3 = (const float*)d_in[16];
    const float* dw0 = (const float*)d_in[17];
    const float* db0 = (const float*)d_in[18];
    const float* dw1 = (const float*)d_in[19];
    const float* db1 = (const float*)d_in[20];
    const float* dw2 = (const float*)d_in[21];
    const float* db2 = (const float*)d_in[22];
    const float* cw1 = (const float*)d_in[23];
    const float* cb1 = (const float*)d_in[24];
    const float* cw2 = (const float*)d_in[25];
    const float* cb2 = (const float*)d_in[26];
    const float* ow  = (const float*)d_in[27];
    const float* ob  = (const float*)d_in[28];
    float* out = (float*)d_out;

    const int Nn = in_sizes[0] / 2;   // 100000
    const int E_ = in_sizes[2] / 2;   // 2000000
    const int NB = (Nn + 255) / 256;  // scan blocks (<=512)
    const int NQ = (Nn * 4 + 255) / 256;  // quad-per-node blocks

    char* ws = (char*)d_ws;
    size_t o = 0;
    float* xs   = (float*)(ws + o); o += (size_t)Nn * XP * sizeof(float);
    int*   cnt  = (int*)  (ws + o); o += (size_t)Nn * sizeof(int);
    int*   offs = (int*)  (ws + o); o += (size_t)Nn * sizeof(int);
    int*   fill = (int*)  (ws + o); o += (size_t)Nn * sizeof(int);
    int*   bsum = (int*)  (ws + o); o += 512 * sizeof(int);
    float* dinv = (float*)(ws + o); o += (size_t)Nn * sizeof(float);
    float* ssb  = (float*)(ws + o); o += (size_t)Nn * sizeof(float);
    int*   es   = (int*)  (ws + o); o += (size_t)E_ * sizeof(int);
    float* wb   = (float*)(ws + o); o += 80 * sizeof(float);

    hipMemsetAsync(cnt, 0, (size_t)Nn * sizeof(int), stream);

    // CSR build first (produces dinv for ffn's prescale)
    deg_kernel<<<(E_ / 4 + 255) / 256, 256, 0, stream>>>(eidx, cnt, E_);
    scan1_kernel<<<NB, 256, 0, stream>>>(cnt, offs, bsum, Nn);
    scan2_kernel<<<1, 512, 0, stream>>>(bsum, NB);
    scan3_kernel<<<NB, 256, 0, stream>>>(offs, bsum, cnt, fill, dinv, Nn);
    scatter_kernel<<<(E_ / 4 + 255) / 256, 256, 0, stream>>>(eidx, eidx + E_, fill, es, E_);

    ffn_kernel<<<(Nn + TM - 1) / TM, 256, 0, stream>>>(
        coords, features, dinv,
        fw0, fb0, fg0, fe0, fw1, fb1, fg1, fe1, fw2, fb2, fg2, fe2, fw3, fb3,
        dw0, db0, dw1, db1, dw2, db2, xs, Nn);

    prep_kernel<<<1, 64, 0, stream>>>(cw2, cb2, ow, ob, wb);
    node1g_kernel<<<NQ, 256, 0, stream>>>(offs, cnt, es, dinv, xs, cw1, cb1, wb, ssb, Nn);
    outg_kernel<<<NQ, 256, 0, stream>>>(offs, cnt, es, dinv, ssb, wb, out, Nn);
}

// Round 8
// 559.236 us; speedup vs baseline: 1.8890x; 1.8890x over previous
//
#include <hip/hip_runtime.h>
#include <hip/hip_bf16.h>
#include <math.h>

#define TM 64   // nodes per ffn tile
#define XP 20   // padded xs row stride (16B-aligned rows)

typedef float v2f __attribute__((ext_vector_type(2)));

__device__ __forceinline__ v2f fma2(v2f a, v2f b, v2f c) {
    return __builtin_elementwise_fma(a, b, c);
}
__device__ __forceinline__ v2f splat2(float s) { return (v2f){s, s}; }
__device__ __forceinline__ v2f max02(v2f a) {
    return (v2f){fmaxf(a.x, 0.0f), fmaxf(a.y, 0.0f)};
}

// ---------------- fused FFN + decoder: coords -> emb, writes xs = dinv * [features, emb, 0pad] ----------------
// lane = node, wave = 32-output slice; weights via wave-uniform s_load (scalar broadcast).
// PERSISTENT grid: exactly 4 blocks/CU, grid-stride over node tiles (fixes cohort-shaped occupancy).
__global__ __launch_bounds__(256) void ffn_kernel(
    const float* __restrict__ coords, const float* __restrict__ features,
    const float* __restrict__ dinv,
    const float* __restrict__ fw0, const float* __restrict__ fb0,
    const float* __restrict__ fg0, const float* __restrict__ fe0,
    const float* __restrict__ fw1, const float* __restrict__ fb1,
    const float* __restrict__ fg1, const float* __restrict__ fe1,
    const float* __restrict__ fw2, const float* __restrict__ fb2,
    const float* __restrict__ fg2, const float* __restrict__ fe2,
    const float* __restrict__ fw3, const float* __restrict__ fb3,
    const float* __restrict__ dw0, const float* __restrict__ db0,
    const float* __restrict__ dw1, const float* __restrict__ db1,
    const float* __restrict__ dw2, const float* __restrict__ db2,
    float* __restrict__ xout, int n_nodes, int ntiles)
{
    __shared__ float hbuf[128][TM];   // [feature][node], 32 KB
    __shared__ float ps1[4][64];      // LN partial sums
    __shared__ float ps2[4][64];      // LN partial sumsq

    const int t    = threadIdx.x;
    const int lane = t & 63;
    const int w    = __builtin_amdgcn_readfirstlane(t >> 6);
    const int jw   = w * 32;

    v2f acc[16];   // outs (jw+2q, jw+2q+1)

    auto lnorm = [&](const float* __restrict__ gam, const float* __restrict__ bet) {
        float s1 = 0.f, s2 = 0.f;
        #pragma unroll
        for (int q = 0; q < 16; q++) {
            s1 += acc[q].x + acc[q].y;
            s2 += acc[q].x * acc[q].x + acc[q].y * acc[q].y;
        }
        ps1[w][lane] = s1; ps2[w][lane] = s2;
        __syncthreads();
        float t1 = ps1[0][lane] + ps1[1][lane] + ps1[2][lane] + ps1[3][lane];
        float t2 = ps2[0][lane] + ps2[1][lane] + ps2[2][lane] + ps2[3][lane];
        float mean = t1 * (1.0f / 128.0f);
        float var  = t2 * (1.0f / 128.0f) - mean * mean;
        float inv  = rsqrtf(var + 1e-5f);
        v2f mean2 = splat2(mean), inv2 = splat2(inv);
        #pragma unroll
        for (int q = 0; q < 16; q++) {
            v2f gm = *(const v2f*)&gam[jw + 2 * q];   // uniform s_load
            v2f bt = *(const v2f*)&bet[jw + 2 * q];
            acc[q] = fma2((acc[q] - mean2) * inv2, gm, bt);
        }
    };

    auto store32 = [&]() {
        #pragma unroll
        for (int q = 0; q < 16; q++) {
            hbuf[jw + 2 * q][lane]     = acc[q].x;
            hbuf[jw + 2 * q + 1][lane] = acc[q].y;
        }
    };

    auto layer128 = [&](const float* __restrict__ W, const float* __restrict__ b) {
        #pragma unroll
        for (int q = 0; q < 16; q++) acc[q] = *(const v2f*)&b[jw + 2 * q];
        #pragma unroll 4
        for (int k = 0; k < 128; k++) {
            v2f av = splat2(hbuf[k][lane]);
            const v2f* W2 = (const v2f*)(W + k * 128 + jw);  // uniform -> s_load
            #pragma unroll
            for (int q = 0; q < 16; q++) acc[q] = fma2(av, W2[q], acc[q]);
        }
    };

    for (int tile = blockIdx.x; tile < ntiles; tile += gridDim.x) {
        const int n0 = tile * TM;
        int g = n0 + lane;
        if (g >= n_nodes) g = n_nodes - 1;

        // ---- layer 0: 2 -> 128, relu, LN ----
        {
            float2 c = *(const float2*)&coords[(size_t)g * 2];
            v2f cx = splat2(c.x), cy = splat2(c.y);
            #pragma unroll
            for (int q = 0; q < 16; q++) {
                int j = jw + 2 * q;
                v2f w0 = *(const v2f*)&fw0[j];
                v2f w1 = *(const v2f*)&fw0[128 + j];
                v2f bb = *(const v2f*)&fb0[j];
                acc[q] = max02(fma2(cx, w0, fma2(cy, w1, bb)));
            }
            lnorm(fg0, fe0);
            store32();
            __syncthreads();
        }

        // ---- layers 1..2: 128 -> 128, relu, LN ----
        layer128(fw1, fb1);
        #pragma unroll
        for (int q = 0; q < 16; q++) acc[q] = max02(acc[q]);
        lnorm(fg1, fe1);
        store32();
        __syncthreads();

        layer128(fw2, fb2);
        #pragma unroll
        for (int q = 0; q < 16; q++) acc[q] = max02(acc[q]);
        lnorm(fg2, fe2);
        store32();
        __syncthreads();

        // ---- layer 3: 128 -> 128, relu only ----
        layer128(fw3, fb3);
        #pragma unroll
        for (int q = 0; q < 16; q++) acc[q] = max02(acc[q]);
        __syncthreads();
        store32();
        __syncthreads();

        // ---- decoder D0: 128 -> 64, tanh ----
        {
            const int j16 = w * 16;
            v2f d0[8];
            #pragma unroll
            for (int q = 0; q < 8; q++) d0[q] = *(const v2f*)&db0[j16 + 2 * q];
            #pragma unroll 4
            for (int k = 0; k < 128; k++) {
                v2f av = splat2(hbuf[k][lane]);
                const v2f* W2 = (const v2f*)(dw0 + k * 64 + j16);
                #pragma unroll
                for (int q = 0; q < 8; q++) d0[q] = fma2(av, W2[q], d0[q]);
            }
            #pragma unroll
            for (int q = 0; q < 8; q++) d0[q] = (v2f){tanhf(d0[q].x), tanhf(d0[q].y)};
            __syncthreads();
            #pragma unroll
            for (int q = 0; q < 8; q++) {
                hbuf[j16 + 2 * q][lane]     = d0[q].x;
                hbuf[j16 + 2 * q + 1][lane] = d0[q].y;
            }
            __syncthreads();
        }

        // ---- decoder D1: 64 -> 32, tanh ----
        {
            const int j8 = w * 8;
            v2f d1[4];
            #pragma unroll
            for (int q = 0; q < 4; q++) d1[q] = *(const v2f*)&db1[j8 + 2 * q];
            #pragma unroll 4
            for (int k = 0; k < 64; k++) {
                v2f av = splat2(hbuf[k][lane]);
                const v2f* W2 = (const v2f*)(dw1 + k * 32 + j8);
                #pragma unroll
                for (int q = 0; q < 4; q++) d1[q] = fma2(av, W2[q], d1[q]);
            }
            #pragma unroll
            for (int q = 0; q < 4; q++) d1[q] = (v2f){tanhf(d1[q].x), tanhf(d1[q].y)};
            __syncthreads();
            #pragma unroll
            for (int q = 0; q < 4; q++) {
                hbuf[j8 + 2 * q][lane]     = d1[q].x;
                hbuf[j8 + 2 * q + 1][lane] = d1[q].y;
            }
            __syncthreads();
        }

        // ---- decoder D2: 32 -> 16, linear ----
        {
            const int j4 = w * 4;
            v2f d2[2];
            #pragma unroll
            for (int q = 0; q < 2; q++) d2[q] = *(const v2f*)&db2[j4 + 2 * q];
            #pragma unroll 4
            for (int k = 0; k < 32; k++) {
                v2f av = splat2(hbuf[k][lane]);
                const v2f* W2 = (const v2f*)(dw2 + k * 16 + j4);
                d2[0] = fma2(av, W2[0], d2[0]);
                d2[1] = fma2(av, W2[1], d2[1]);
            }
            __syncthreads();
            hbuf[j4 + 0][lane] = d2[0].x;
            hbuf[j4 + 1][lane] = d2[0].y;
            hbuf[j4 + 2][lane] = d2[1].x;
            hbuf[j4 + 3][lane] = d2[1].y;
            __syncthreads();
        }

        // ---- write xs = dinv * [features(3), emb(16), pad0], stride XP=20 ----
        // lane = node, iterate j: hbuf reads conflict-free
        {
            const int nn = t & 63;
            const int jg = t >> 6;             // 0..3, each handles 5 js
            int gg = n0 + nn;
            if (gg < n_nodes) {
                float dgg = dinv[gg];
                #pragma unroll
                for (int it = 0; it < 5; it++) {
                    int j = jg * 5 + it;
                    float v = (j < 3) ? features[(size_t)gg * 3 + j]
                                      : (j < 19 ? hbuf[j - 3][nn] : 0.0f);
                    xout[(size_t)gg * XP + j] = v * dgg;
                }
            }
        }
        __syncthreads();   // hbuf reads done before next tile overwrites
    }
}

// ---------------- CSR build ----------------
__global__ void deg_kernel(const int* __restrict__ row, int* __restrict__ cnt, int E_) {
    int e4 = (blockIdx.x * blockDim.x + threadIdx.x) * 4;
    if (e4 + 3 < E_) {
        int4 r = *(const int4*)&row[e4];
        atomicAdd(&cnt[r.x], 1); atomicAdd(&cnt[r.y], 1);
        atomicAdd(&cnt[r.z], 1); atomicAdd(&cnt[r.w], 1);
    } else {
        for (int e = e4; e < E_; e++) atomicAdd(&cnt[row[e]], 1);
    }
}

__global__ void scan1_kernel(const int* __restrict__ cnt, int* __restrict__ offs,
                             int* __restrict__ bsum, int n) {
    __shared__ int tmp[256];
    int t = threadIdx.x, b = blockIdx.x, i = b * 256 + t;
    int v = (i < n) ? cnt[i] : 0;
    tmp[t] = v; __syncthreads();
    #pragma unroll
    for (int d = 1; d < 256; d <<= 1) {
        int add = (t >= d) ? tmp[t - d] : 0;
        __syncthreads();
        tmp[t] += add;
        __syncthreads();
    }
    if (i < n) offs[i] = tmp[t] - v;
    if (t == 255) bsum[b] = tmp[t];
}

__global__ void scan2_kernel(int* __restrict__ bsum, int B) {
    __shared__ int tmp[512];
    int t = threadIdx.x;
    tmp[t] = (t < B) ? bsum[t] : 0; __syncthreads();
    #pragma unroll
    for (int d = 1; d < 512; d <<= 1) {
        int add = (t >= d) ? tmp[t - d] : 0;
        __syncthreads();
        tmp[t] += add;
        __syncthreads();
    }
    if (t < B) bsum[t] = tmp[t];
}

__global__ void scan3_kernel(int* __restrict__ offs, const int* __restrict__ bsum,
                             const int* __restrict__ cnt, int* __restrict__ fill,
                             float* __restrict__ dinv, int n) {
    int i = blockIdx.x * blockDim.x + threadIdx.x;
    if (i >= n) return;
    int b = i >> 8;
    int base = (b > 0) ? bsum[b - 1] : 0;
    int o = offs[i] + base;
    offs[i] = o;
    fill[i] = o;
    dinv[i] = rsqrtf((float)cnt[i] + 1.0f);
}

__global__ void scatter_kernel(const int* __restrict__ row, const int* __restrict__ col,
                               int* __restrict__ fill, int* __restrict__ es, int E_) {
    int e4 = (blockIdx.x * blockDim.x + threadIdx.x) * 4;
    if (e4 + 3 < E_) {
        int4 r = *(const int4*)&row[e4];
        int4 c = *(const int4*)&col[e4];
        es[atomicAdd(&fill[r.x], 1)] = c.x;
        es[atomicAdd(&fill[r.y], 1)] = c.y;
        es[atomicAdd(&fill[r.z], 1)] = c.z;
        es[atomicAdd(&fill[r.w], 1)] = c.w;
    } else {
        for (int e = e4; e < E_; e++) {
            int p = atomicAdd(&fill[row[e]], 1);
            es[p] = col[e];
        }
    }
}

// w_eff = cw2 @ ow (64), b_eff = cb2 @ ow + ob
__global__ void prep_kernel(const float* __restrict__ cw2, const float* __restrict__ cb2,
                            const float* __restrict__ ow, const float* __restrict__ ob,
                            float* __restrict__ wb) {
    int i = threadIdx.x;
    if (i < 64) {
        float a = 0.f;
        for (int j = 0; j < 64; j++) a += cw2[i * 64 + j] * ow[j];
        wb[i] = a;
    }
    if (i == 0) {
        float bb = 0.f;
        for (int j = 0; j < 64; j++) bb += cb2[j] * ow[j];
        wb[64] = bb + ob[0];
    }
}

// quad (4 lanes) per node: gather Σ xs[c] (float4 adds), combine, ×di, matmul 19x64 split
// 16 outs/lane, relu, dot w_eff, reduce -> ss[i] = dinv[i]*s[i]
__global__ __launch_bounds__(256) void node1g_kernel(
    const int* __restrict__ offs, const int* __restrict__ cnt, const int* __restrict__ es,
    const float* __restrict__ dinv, const float* __restrict__ xs,
    const float* __restrict__ cw1, const float* __restrict__ cb1,
    const float* __restrict__ wb, float* __restrict__ ss, int n)
{
    __shared__ float w[XP * 64];
    __shared__ float bbs[64];
    __shared__ float wes[64];
    for (int i = threadIdx.x; i < 19 * 64; i += 256) w[i] = cw1[i];
    for (int i = threadIdx.x; i < 64; i += 256) {
        w[19 * 64 + i] = 0.0f;        // pad row
        bbs[i] = cb1[i];
        wes[i] = wb[i];
    }
    __syncthreads();
    const int t  = threadIdx.x;
    const int ql = t & 3;
    const int i  = blockIdx.x * 64 + (t >> 2);
    if (i >= n) return;
    const float di = dinv[i];

    float4 a4[5];
    if (ql == 0) {  // self term xs[i]
        const float4* xi = (const float4*)(xs + (size_t)i * XP);
        #pragma unroll
        for (int q = 0; q < 5; q++) a4[q] = xi[q];
    } else {
        #pragma unroll
        for (int q = 0; q < 5; q++) a4[q] = make_float4(0.f, 0.f, 0.f, 0.f);
    }
    const int st = offs[i], dg = cnt[i];
    for (int e = ql; e < dg; e += 4) {
        int c = es[st + e];
        const float4* xc = (const float4*)(xs + (size_t)c * XP);
        #pragma unroll
        for (int q = 0; q < 5; q++) {
            float4 v = xc[q];
            a4[q].x += v.x; a4[q].y += v.y; a4[q].z += v.z; a4[q].w += v.w;
        }
    }
    // quad reduce + scale by di
    float a19[XP];
    #pragma unroll
    for (int q = 0; q < 5; q++) {
        float vx = a4[q].x, vy = a4[q].y, vz = a4[q].z, vw = a4[q].w;
        vx += __shfl_xor(vx, 1); vy += __shfl_xor(vy, 1);
        vz += __shfl_xor(vz, 1); vw += __shfl_xor(vw, 1);
        vx += __shfl_xor(vx, 2); vy += __shfl_xor(vy, 2);
        vz += __shfl_xor(vz, 2); vw += __shfl_xor(vw, 2);
        a19[4 * q]     = vx * di;
        a19[4 * q + 1] = vy * di;
        a19[4 * q + 2] = vz * di;
        a19[4 * q + 3] = vw * di;
    }

    // matmul: this lane's 16 outputs j in [ql*16, ql*16+16)
    const int j0 = ql * 16;
    v2f am[8];
    const v2f* w2  = (const v2f*)w;
    const v2f* bb2 = (const v2f*)bbs;
    #pragma unroll
    for (int q = 0; q < 8; q++) am[q] = bb2[j0 / 2 + q];
    #pragma unroll
    for (int k = 0; k < 19; k++) {
        v2f v = splat2(a19[k]);
        #pragma unroll
        for (int q = 0; q < 8; q++) am[q] = fma2(v, w2[k * 32 + j0 / 2 + q], am[q]);
    }
    const v2f* we2 = (const v2f*)wes;
    v2f sv2 = {0.f, 0.f};
    #pragma unroll
    for (int q = 0; q < 8; q++) sv2 = fma2(max02(am[q]), we2[j0 / 2 + q], sv2);
    float sv = sv2.x + sv2.y;
    sv += __shfl_xor(sv, 1);
    sv += __shfl_xor(sv, 2);
    if (ql == 0) ss[i] = di * sv;
}

// quad per node: out[i] = b_eff + di * (ss[i] + Σ ss[c])
__global__ __launch_bounds__(256) void outg_kernel(
    const int* __restrict__ offs, const int* __restrict__ cnt, const int* __restrict__ es,
    const float* __restrict__ dinv, const float* __restrict__ ss,
    const float* __restrict__ wb, float* __restrict__ out, int n)
{
    const int t  = threadIdx.x;
    const int ql = t & 3;
    const int i  = blockIdx.x * 64 + (t >> 2);
    if (i >= n) return;
    const int st = offs[i], dg = cnt[i];
    float sum = (ql == 0) ? ss[i] : 0.f;
    for (int e = ql; e < dg; e += 4) {
        int c = es[st + e];
        sum += ss[c];
    }
    sum += __shfl_xor(sum, 1);
    sum += __shfl_xor(sum, 2);
    if (ql == 0) out[i] = wb[64] + dinv[i] * sum;
}

extern "C" void kernel_launch(void* const* d_in, const int* in_sizes, int n_in,
                              void* d_out, int out_size, void* d_ws, size_t ws_size,
                              hipStream_t stream) {
    const float* coords   = (const float*)d_in[0];
    const float* features = (const float*)d_in[1];
    const int*   eidx     = (const int*)d_in[2];
    const float* fw0 = (const float*)d_in[3];
    const float* fb0 = (const float*)d_in[4];
    const float* fg0 = (const float*)d_in[5];
    const float* fe0 = (const float*)d_in[6];
    const float* fw1 = (const float*)d_in[7];
    const float* fb1 = (const float*)d_in[8];
    const float* fg1 = (const float*)d_in[9];
    const float* fe1 = (const float*)d_in[10];
    const float* fw2 = (const float*)d_in[11];
    const float* fb2 = (const float*)d_in[12];
    const float* fg2 = (const float*)d_in[13];
    const float* fe2 = (const float*)d_in[14];
    const float* fw3 = (const float*)d_in[15];
    const float* fb3 = (const float*)d_in[16];
    const float* dw0 = (const float*)d_in[17];
    const float* db0 = (const float*)d_in[18];
    const float* dw1 = (const float*)d_in[19];
    const float* db1 = (const float*)d_in[20];
    const float* dw2 = (const float*)d_in[21];
    const float* db2 = (const float*)d_in[22];
    const float* cw1 = (const float*)d_in[23];
    const float* cb1 = (const float*)d_in[24];
    const float* cw2 = (const float*)d_in[25];
    const float* cb2 = (const float*)d_in[26];
    const float* ow  = (const float*)d_in[27];
    const float* ob  = (const float*)d_in[28];
    float* out = (float*)d_out;

    const int Nn = in_sizes[0] / 2;   // 100000
    const int E_ = in_sizes[2] / 2;   // 2000000
    const int NB = (Nn + 255) / 256;  // scan blocks (<=512)
    const int NQ = (Nn * 4 + 255) / 256;  // quad-per-node blocks
    const int NT = (Nn + TM - 1) / TM;    // ffn node tiles

    char* ws = (char*)d_ws;
    size_t o = 0;
    float* xs   = (float*)(ws + o); o += (size_t)Nn * XP * sizeof(float);
    int*   cnt  = (int*)  (ws + o); o += (size_t)Nn * sizeof(int);
    int*   offs = (int*)  (ws + o); o += (size_t)Nn * sizeof(int);
    int*   fill = (int*)  (ws + o); o += (size_t)Nn * sizeof(int);
    int*   bsum = (int*)  (ws + o); o += 512 * sizeof(int);
    float* dinv = (float*)(ws + o); o += (size_t)Nn * sizeof(float);
    float* ssb  = (float*)(ws + o); o += (size_t)Nn * sizeof(float);
    int*   es   = (int*)  (ws + o); o += (size_t)E_ * sizeof(int);
    float* wb   = (float*)(ws + o); o += 80 * sizeof(float);

    hipMemsetAsync(cnt, 0, (size_t)Nn * sizeof(int), stream);

    // CSR build first (produces dinv for ffn's prescale)
    deg_kernel<<<(E_ / 4 + 255) / 256, 256, 0, stream>>>(eidx, cnt, E_);
    scan1_kernel<<<NB, 256, 0, stream>>>(cnt, offs, bsum, Nn);
    scan2_kernel<<<1, 512, 0, stream>>>(bsum, NB);
    scan3_kernel<<<NB, 256, 0, stream>>>(offs, bsum, cnt, fill, dinv, Nn);
    scatter_kernel<<<(E_ / 4 + 255) / 256, 256, 0, stream>>>(eidx, eidx + E_, fill, es, E_);

    // persistent: 4 blocks/CU x 256 CUs
    ffn_kernel<<<1024, 256, 0, stream>>>(
        coords, features, dinv,
        fw0, fb0, fg0, fe0, fw1, fb1, fg1, fe1, fw2, fb2, fg2, fe2, fw3, fb3,
        dw0, db0, dw1, db1, dw2, db2, xs, Nn, NT);

    prep_kernel<<<1, 64, 0, stream>>>(cw2, cb2, ow, ob, wb);
    node1g_kernel<<<NQ, 256, 0, stream>>>(offs, cnt, es, dinv, xs, cw1, cb1, wb, ssb, Nn);
    outg_kernel<<<NQ, 256, 0, stream>>>(offs, cnt, es, dinv, ssb, wb, out, Nn);
}

// Round 9
// 475.417 us; speedup vs baseline: 2.2220x; 1.1763x over previous
//
#include <hip/hip_runtime.h>
#include <hip/hip_bf16.h>
#include <math.h>

#define TM 64   // nodes per ffn tile
#define XP 20   // padded xs row stride (16B-aligned rows)

typedef float v2f __attribute__((ext_vector_type(2)));

__device__ __forceinline__ v2f fma2(v2f a, v2f b, v2f c) {
    return __builtin_elementwise_fma(a, b, c);
}
__device__ __forceinline__ v2f splat2(float s) { return (v2f){s, s}; }
__device__ __forceinline__ v2f max02(v2f a) {
    return (v2f){fmaxf(a.x, 0.0f), fmaxf(a.y, 0.0f)};
}

// ---------------- fused FFN + decoder: coords -> emb, writes xs = dinv * [features, emb, 0pad] ----------------
// 512 threads = 8 waves/block, TM=64 nodes, wave = 16-output slice.
// LDS 32KB+2KB -> 4 blocks/CU x 8 waves = 32 waves/CU (100% theoretical occupancy).
// lane = node: hbuf accesses conflict-free; weights wave-uniform -> s_load broadcasts.
__global__ __launch_bounds__(512) void ffn_kernel(
    const float* __restrict__ coords, const float* __restrict__ features,
    const float* __restrict__ dinv,
    const float* __restrict__ fw0, const float* __restrict__ fb0,
    const float* __restrict__ fg0, const float* __restrict__ fe0,
    const float* __restrict__ fw1, const float* __restrict__ fb1,
    const float* __restrict__ fg1, const float* __restrict__ fe1,
    const float* __restrict__ fw2, const float* __restrict__ fb2,
    const float* __restrict__ fg2, const float* __restrict__ fe2,
    const float* __restrict__ fw3, const float* __restrict__ fb3,
    const float* __restrict__ dw0, const float* __restrict__ db0,
    const float* __restrict__ dw1, const float* __restrict__ db1,
    const float* __restrict__ dw2, const float* __restrict__ db2,
    float* __restrict__ xout, int n_nodes)
{
    __shared__ float hbuf[128][TM];   // [feature][node], 32 KB
    __shared__ float ps1[8][64];      // LN partial sums   (2 KB)
    __shared__ float ps2[8][64];      // LN partial sumsq  (2 KB)

    const int t    = threadIdx.x;
    const int lane = t & 63;
    const int w    = __builtin_amdgcn_readfirstlane(t >> 6);  // 0..7
    const int jw   = w * 16;                                   // this wave's 16 outs
    const int n0   = blockIdx.x * TM;

    int g = n0 + lane;
    if (g >= n_nodes) g = n_nodes - 1;

    v2f acc[8];   // outs (jw+2q, jw+2q+1)

    auto lnorm = [&](const float* __restrict__ gam, const float* __restrict__ bet) {
        float s1 = 0.f, s2 = 0.f;
        #pragma unroll
        for (int q = 0; q < 8; q++) {
            s1 += acc[q].x + acc[q].y;
            s2 += acc[q].x * acc[q].x + acc[q].y * acc[q].y;
        }
        ps1[w][lane] = s1; ps2[w][lane] = s2;
        __syncthreads();
        float t1 = 0.f, t2 = 0.f;
        #pragma unroll
        for (int ww = 0; ww < 8; ww++) { t1 += ps1[ww][lane]; t2 += ps2[ww][lane]; }
        float mean = t1 * (1.0f / 128.0f);
        float var  = t2 * (1.0f / 128.0f) - mean * mean;
        float inv  = rsqrtf(var + 1e-5f);
        v2f mean2 = splat2(mean), inv2 = splat2(inv);
        #pragma unroll
        for (int q = 0; q < 8; q++) {
            v2f gm = *(const v2f*)&gam[jw + 2 * q];   // uniform s_load
            v2f bt = *(const v2f*)&bet[jw + 2 * q];
            acc[q] = fma2((acc[q] - mean2) * inv2, gm, bt);
        }
    };

    auto store16 = [&]() {
        #pragma unroll
        for (int q = 0; q < 8; q++) {
            hbuf[jw + 2 * q][lane]     = acc[q].x;
            hbuf[jw + 2 * q + 1][lane] = acc[q].y;
        }
    };

    auto layer128 = [&](const float* __restrict__ W, const float* __restrict__ b) {
        #pragma unroll
        for (int q = 0; q < 8; q++) acc[q] = *(const v2f*)&b[jw + 2 * q];
        #pragma unroll 4
        for (int k = 0; k < 128; k++) {
            v2f av = splat2(hbuf[k][lane]);
            const v2f* W2 = (const v2f*)(W + k * 128 + jw);  // uniform -> s_load
            #pragma unroll
            for (int q = 0; q < 8; q++) acc[q] = fma2(av, W2[q], acc[q]);
        }
    };

    // ---- layer 0: 2 -> 128, relu, LN ----
    {
        float2 c = *(const float2*)&coords[(size_t)g * 2];
        v2f cx = splat2(c.x), cy = splat2(c.y);
        #pragma unroll
        for (int q = 0; q < 8; q++) {
            int j = jw + 2 * q;
            v2f w0 = *(const v2f*)&fw0[j];
            v2f w1 = *(const v2f*)&fw0[128 + j];
            v2f bb = *(const v2f*)&fb0[j];
            acc[q] = max02(fma2(cx, w0, fma2(cy, w1, bb)));
        }
        lnorm(fg0, fe0);
        store16();
        __syncthreads();
    }

    // ---- layers 1..2: 128 -> 128, relu, LN ----
    layer128(fw1, fb1);
    #pragma unroll
    for (int q = 0; q < 8; q++) acc[q] = max02(acc[q]);
    lnorm(fg1, fe1);           // internal barrier covers WAR on hbuf
    store16();
    __syncthreads();

    layer128(fw2, fb2);
    #pragma unroll
    for (int q = 0; q < 8; q++) acc[q] = max02(acc[q]);
    lnorm(fg2, fe2);
    store16();
    __syncthreads();

    // ---- layer 3: 128 -> 128, relu only ----
    layer128(fw3, fb3);
    #pragma unroll
    for (int q = 0; q < 8; q++) acc[q] = max02(acc[q]);
    __syncthreads();
    store16();
    __syncthreads();

    // ---- decoder D0: 128 -> 64, tanh ----
    {
        const int j8 = w * 8;
        v2f d0[4];
        #pragma unroll
        for (int q = 0; q < 4; q++) d0[q] = *(const v2f*)&db0[j8 + 2 * q];
        #pragma unroll 4
        for (int k = 0; k < 128; k++) {
            v2f av = splat2(hbuf[k][lane]);
            const v2f* W2 = (const v2f*)(dw0 + k * 64 + j8);
            #pragma unroll
            for (int q = 0; q < 4; q++) d0[q] = fma2(av, W2[q], d0[q]);
        }
        #pragma unroll
        for (int q = 0; q < 4; q++) d0[q] = (v2f){tanhf(d0[q].x), tanhf(d0[q].y)};
        __syncthreads();
        #pragma unroll
        for (int q = 0; q < 4; q++) {
            hbuf[j8 + 2 * q][lane]     = d0[q].x;
            hbuf[j8 + 2 * q + 1][lane] = d0[q].y;
        }
        __syncthreads();
    }

    // ---- decoder D1: 64 -> 32, tanh ----
    {
        const int j4 = w * 4;
        v2f d1[2];
        #pragma unroll
        for (int q = 0; q < 2; q++) d1[q] = *(const v2f*)&db1[j4 + 2 * q];
        #pragma unroll 4
        for (int k = 0; k < 64; k++) {
            v2f av = splat2(hbuf[k][lane]);
            const v2f* W2 = (const v2f*)(dw1 + k * 32 + j4);
            d1[0] = fma2(av, W2[0], d1[0]);
            d1[1] = fma2(av, W2[1], d1[1]);
        }
        #pragma unroll
        for (int q = 0; q < 2; q++) d1[q] = (v2f){tanhf(d1[q].x), tanhf(d1[q].y)};
        __syncthreads();
        #pragma unroll
        for (int q = 0; q < 2; q++) {
            hbuf[j4 + 2 * q][lane]     = d1[q].x;
            hbuf[j4 + 2 * q + 1][lane] = d1[q].y;
        }
        __syncthreads();
    }

    // ---- decoder D2: 32 -> 16, linear (each wave does 2 outs) ----
    {
        const int j2 = w * 2;
        v2f d2 = *(const v2f*)&db2[j2];
        #pragma unroll 4
        for (int k = 0; k < 32; k++) {
            v2f av = splat2(hbuf[k][lane]);
            const v2f* W2 = (const v2f*)(dw2 + k * 16 + j2);
            d2 = fma2(av, W2[0], d2);
        }
        __syncthreads();
        hbuf[j2 + 0][lane] = d2.x;
        hbuf[j2 + 1][lane] = d2.y;
        __syncthreads();
    }

    // ---- write xs = dinv * [features(3), emb(16), pad0], stride XP=20 ----
    // lane = node, iterate j: hbuf reads conflict-free
    {
        const int nn = t & 63;
        const int jg = t >> 6;             // 0..7, each handles 3 js (24 >= 20)
        int gg = n0 + nn;
        if (gg < n_nodes) {
            float dgg = dinv[gg];
            #pragma unroll
            for (int it = 0; it < 3; it++) {
                int j = jg * 3 + it;
                if (j < XP) {
                    float v = (j < 3) ? features[(size_t)gg * 3 + j]
                                      : (j < 19 ? hbuf[j - 3][nn] : 0.0f);
                    xout[(size_t)gg * XP + j] = v * dgg;
                }
            }
        }
    }
}

// ---------------- CSR build ----------------
__global__ void deg_kernel(const int* __restrict__ row, int* __restrict__ cnt, int E_) {
    int e4 = (blockIdx.x * blockDim.x + threadIdx.x) * 4;
    if (e4 + 3 < E_) {
        int4 r = *(const int4*)&row[e4];
        atomicAdd(&cnt[r.x], 1); atomicAdd(&cnt[r.y], 1);
        atomicAdd(&cnt[r.z], 1); atomicAdd(&cnt[r.w], 1);
    } else {
        for (int e = e4; e < E_; e++) atomicAdd(&cnt[row[e]], 1);
    }
}

__global__ void scan1_kernel(const int* __restrict__ cnt, int* __restrict__ offs,
                             int* __restrict__ bsum, int n) {
    __shared__ int tmp[256];
    int t = threadIdx.x, b = blockIdx.x, i = b * 256 + t;
    int v = (i < n) ? cnt[i] : 0;
    tmp[t] = v; __syncthreads();
    #pragma unroll
    for (int d = 1; d < 256; d <<= 1) {
        int add = (t >= d) ? tmp[t - d] : 0;
        __syncthreads();
        tmp[t] += add;
        __syncthreads();
    }
    if (i < n) offs[i] = tmp[t] - v;
    if (t == 255) bsum[b] = tmp[t];
}

__global__ void scan2_kernel(int* __restrict__ bsum, int B) {
    __shared__ int tmp[512];
    int t = threadIdx.x;
    tmp[t] = (t < B) ? bsum[t] : 0; __syncthreads();
    #pragma unroll
    for (int d = 1; d < 512; d <<= 1) {
        int add = (t >= d) ? tmp[t - d] : 0;
        __syncthreads();
        tmp[t] += add;
        __syncthreads();
    }
    if (t < B) bsum[t] = tmp[t];
}

__global__ void scan3_kernel(int* __restrict__ offs, const int* __restrict__ bsum,
                             const int* __restrict__ cnt, int* __restrict__ fill,
                             float* __restrict__ dinv, int n) {
    int i = blockIdx.x * blockDim.x + threadIdx.x;
    if (i >= n) return;
    int b = i >> 8;
    int base = (b > 0) ? bsum[b - 1] : 0;
    int o = offs[i] + base;
    offs[i] = o;
    fill[i] = o;
    dinv[i] = rsqrtf((float)cnt[i] + 1.0f);
}

__global__ void scatter_kernel(const int* __restrict__ row, const int* __restrict__ col,
                               int* __restrict__ fill, int* __restrict__ es, int E_) {
    int e4 = (blockIdx.x * blockDim.x + threadIdx.x) * 4;
    if (e4 + 3 < E_) {
        int4 r = *(const int4*)&row[e4];
        int4 c = *(const int4*)&col[e4];
        es[atomicAdd(&fill[r.x], 1)] = c.x;
        es[atomicAdd(&fill[r.y], 1)] = c.y;
        es[atomicAdd(&fill[r.z], 1)] = c.z;
        es[atomicAdd(&fill[r.w], 1)] = c.w;
    } else {
        for (int e = e4; e < E_; e++) {
            int p = atomicAdd(&fill[row[e]], 1);
            es[p] = col[e];
        }
    }
}

// w_eff = cw2 @ ow (64), b_eff = cb2 @ ow + ob
__global__ void prep_kernel(const float* __restrict__ cw2, const float* __restrict__ cb2,
                            const float* __restrict__ ow, const float* __restrict__ ob,
                            float* __restrict__ wb) {
    int i = threadIdx.x;
    if (i < 64) {
        float a = 0.f;
        for (int j = 0; j < 64; j++) a += cw2[i * 64 + j] * ow[j];
        wb[i] = a;
    }
    if (i == 0) {
        float bb = 0.f;
        for (int j = 0; j < 64; j++) bb += cb2[j] * ow[j];
        wb[64] = bb + ob[0];
    }
}

// quad (4 lanes) per node: gather Σ xs[c] (float4 adds), combine, ×di, matmul 19x64 split
// 16 outs/lane, relu, dot w_eff, reduce -> ss[i] = dinv[i]*s[i]
__global__ __launch_bounds__(256) void node1g_kernel(
    const int* __restrict__ offs, const int* __restrict__ cnt, const int* __restrict__ es,
    const float* __restrict__ dinv, const float* __restrict__ xs,
    const float* __restrict__ cw1, const float* __restrict__ cb1,
    const float* __restrict__ wb, float* __restrict__ ss, int n)
{
    __shared__ float w[XP * 64];
    __shared__ float bbs[64];
    __shared__ float wes[64];
    for (int i = threadIdx.x; i < 19 * 64; i += 256) w[i] = cw1[i];
    for (int i = threadIdx.x; i < 64; i += 256) {
        w[19 * 64 + i] = 0.0f;        // pad row
        bbs[i] = cb1[i];
        wes[i] = wb[i];
    }
    __syncthreads();
    const int t  = threadIdx.x;
    const int ql = t & 3;
    const int i  = blockIdx.x * 64 + (t >> 2);
    if (i >= n) return;
    const float di = dinv[i];

    float4 a4[5];
    if (ql == 0) {  // self term xs[i]
        const float4* xi = (const float4*)(xs + (size_t)i * XP);
        #pragma unroll
        for (int q = 0; q < 5; q++) a4[q] = xi[q];
    } else {
        #pragma unroll
        for (int q = 0; q < 5; q++) a4[q] = make_float4(0.f, 0.f, 0.f, 0.f);
    }
    const int st = offs[i], dg = cnt[i];
    for (int e = ql; e < dg; e += 4) {
        int c = es[st + e];
        const float4* xc = (const float4*)(xs + (size_t)c * XP);
        #pragma unroll
        for (int q = 0; q < 5; q++) {
            float4 v = xc[q];
            a4[q].x += v.x; a4[q].y += v.y; a4[q].z += v.z; a4[q].w += v.w;
        }
    }
    // quad reduce + scale by di
    float a19[XP];
    #pragma unroll
    for (int q = 0; q < 5; q++) {
        float vx = a4[q].x, vy = a4[q].y, vz = a4[q].z, vw = a4[q].w;
        vx += __shfl_xor(vx, 1); vy += __shfl_xor(vy, 1);
        vz += __shfl_xor(vz, 1); vw += __shfl_xor(vw, 1);
        vx += __shfl_xor(vx, 2); vy += __shfl_xor(vy, 2);
        vz += __shfl_xor(vz, 2); vw += __shfl_xor(vw, 2);
        a19[4 * q]     = vx * di;
        a19[4 * q + 1] = vy * di;
        a19[4 * q + 2] = vz * di;
        a19[4 * q + 3] = vw * di;
    }

    // matmul: this lane's 16 outputs j in [ql*16, ql*16+16)
    const int j0 = ql * 16;
    v2f am[8];
    const v2f* w2  = (const v2f*)w;
    const v2f* bb2 = (const v2f*)bbs;
    #pragma unroll
    for (int q = 0; q < 8; q++) am[q] = bb2[j0 / 2 + q];
    #pragma unroll
    for (int k = 0; k < 19; k++) {
        v2f v = splat2(a19[k]);
        #pragma unroll
        for (int q = 0; q < 8; q++) am[q] = fma2(v, w2[k * 32 + j0 / 2 + q], am[q]);
    }
    const v2f* we2 = (const v2f*)wes;
    v2f sv2 = {0.f, 0.f};
    #pragma unroll
    for (int q = 0; q < 8; q++) sv2 = fma2(max02(am[q]), we2[j0 / 2 + q], sv2);
    float sv = sv2.x + sv2.y;
    sv += __shfl_xor(sv, 1);
    sv += __shfl_xor(sv, 2);
    if (ql == 0) ss[i] = di * sv;
}

// quad per node: out[i] = b_eff + di * (ss[i] + Σ ss[c])
__global__ __launch_bounds__(256) void outg_kernel(
    const int* __restrict__ offs, const int* __restrict__ cnt, const int* __restrict__ es,
    const float* __restrict__ dinv, const float* __restrict__ ss,
    const float* __restrict__ wb, float* __restrict__ out, int n)
{
    const int t  = threadIdx.x;
    const int ql = t & 3;
    const int i  = blockIdx.x * 64 + (t >> 2);
    if (i >= n) return;
    const int st = offs[i], dg = cnt[i];
    float sum = (ql == 0) ? ss[i] : 0.f;
    for (int e = ql; e < dg; e += 4) {
        int c = es[st + e];
        sum += ss[c];
    }
    sum += __shfl_xor(sum, 1);
    sum += __shfl_xor(sum, 2);
    if (ql == 0) out[i] = wb[64] + dinv[i] * sum;
}

extern "C" void kernel_launch(void* const* d_in, const int* in_sizes, int n_in,
                              void* d_out, int out_size, void* d_ws, size_t ws_size,
                              hipStream_t stream) {
    const float* coords   = (const float*)d_in[0];
    const float* features = (const float*)d_in[1];
    const int*   eidx     = (const int*)d_in[2];
    const float* fw0 = (const float*)d_in[3];
    const float* fb0 = (const float*)d_in[4];
    const float* fg0 = (const float*)d_in[5];
    const float* fe0 = (const float*)d_in[6];
    const float* fw1 = (const float*)d_in[7];
    const float* fb1 = (const float*)d_in[8];
    const float* fg1 = (const float*)d_in[9];
    const float* fe1 = (const float*)d_in[10];
    const float* fw2 = (const float*)d_in[11];
    const float* fb2 = (const float*)d_in[12];
    const float* fg2 = (const float*)d_in[13];
    const float* fe2 = (const float*)d_in[14];
    const float* fw3 = (const float*)d_in[15];
    const float* fb3 = (const float*)d_in[16];
    const float* dw0 = (const float*)d_in[17];
    const float* db0 = (const float*)d_in[18];
    const float* dw1 = (const float*)d_in[19];
    const float* db1 = (const float*)d_in[20];
    const float* dw2 = (const float*)d_in[21];
    const float* db2 = (const float*)d_in[22];
    const float* cw1 = (const float*)d_in[23];
    const float* cb1 = (const float*)d_in[24];
    const float* cw2 = (const float*)d_in[25];
    const float* cb2 = (const float*)d_in[26];
    const float* ow  = (const float*)d_in[27];
    const float* ob  = (const float*)d_in[28];
    float* out = (float*)d_out;

    const int Nn = in_sizes[0] / 2;   // 100000
    const int E_ = in_sizes[2] / 2;   // 2000000
    const int NB = (Nn + 255) / 256;  // scan blocks (<=512)
    const int NQ = (Nn * 4 + 255) / 256;  // quad-per-node blocks
    const int NT = (Nn + TM - 1) / TM;    // ffn node tiles

    char* ws = (char*)d_ws;
    size_t o = 0;
    float* xs   = (float*)(ws + o); o += (size_t)Nn * XP * sizeof(float);
    int*   cnt  = (int*)  (ws + o); o += (size_t)Nn * sizeof(int);
    int*   offs = (int*)  (ws + o); o += (size_t)Nn * sizeof(int);
    int*   fill = (int*)  (ws + o); o += (size_t)Nn * sizeof(int);
    int*   bsum = (int*)  (ws + o); o += 512 * sizeof(int);
    float* dinv = (float*)(ws + o); o += (size_t)Nn * sizeof(float);
    float* ssb  = (float*)(ws + o); o += (size_t)Nn * sizeof(float);
    int*   es   = (int*)  (ws + o); o += (size_t)E_ * sizeof(int);
    float* wb   = (float*)(ws + o); o += 80 * sizeof(float);

    hipMemsetAsync(cnt, 0, (size_t)Nn * sizeof(int), stream);

    // CSR build first (produces dinv for ffn's prescale)
    deg_kernel<<<(E_ / 4 + 255) / 256, 256, 0, stream>>>(eidx, cnt, E_);
    scan1_kernel<<<NB, 256, 0, stream>>>(cnt, offs, bsum, Nn);
    scan2_kernel<<<1, 512, 0, stream>>>(bsum, NB);
    scan3_kernel<<<NB, 256, 0, stream>>>(offs, bsum, cnt, fill, dinv, Nn);
    scatter_kernel<<<(E_ / 4 + 255) / 256, 256, 0, stream>>>(eidx, eidx + E_, fill, es, E_);

    ffn_kernel<<<NT, 512, 0, stream>>>(
        coords, features, dinv,
        fw0, fb0, fg0, fe0, fw1, fb1, fg1, fe1, fw2, fb2, fg2, fe2, fw3, fb3,
        dw0, db0, dw1, db1, dw2, db2, xs, Nn);

    prep_kernel<<<1, 64, 0, stream>>>(cw2, cb2, ow, ob, wb);
    node1g_kernel<<<NQ, 256, 0, stream>>>(offs, cnt, es, dinv, xs, cw1, cb1, wb, ssb, Nn);
    outg_kernel<<<NQ, 256, 0, stream>>>(offs, cnt, es, dinv, ssb, wb, out, Nn);
}